// Round 8
// baseline (189.821 us; speedup 1.0000x reference)
//
#include <hip/hip_runtime.h>

// Problem constants (fixed by setup_inputs): (16,3,512,512) f32, PATCH=16
constexpr int IMG         = 512;
constexpr int PLANE_ELEMS = IMG * IMG;          // 262144
constexpr int TOTAL_PATCH = 48 * 1024;          // 49152
constexpr long long TOTAL_ELEMS = 12582912LL;   // 48 * 262144
constexpr float  EPS = 1e-6f;
// 1 wave = 4 horizontally-adjacent patches; 4 waves/block -> 16 patches/block
constexpr int NBLOCKS = TOTAL_PATCH / 16;       // 3072

typedef float floatx4 __attribute__((ext_vector_type(4)));  // native vec for NT store

template <int CTRL>
__device__ __forceinline__ float dpp_add(float v) {
    int x = __builtin_amdgcn_update_dpp(0, __float_as_int(v), CTRL, 0xF, 0xF, false);
    return v + __int_as_float(x);
}

// Segmented butterfly: sums over lane bits {0,1,4,5}; bits {2,3} (= patch id)
// preserved. Every lane ends with its own patch's 16-lane total.
__device__ __forceinline__ float seg_reduce(float v) {
    v = dpp_add<0xB1>(v);   // quad_perm [1,0,3,2] : xor lane bit 0
    v = dpp_add<0x4E>(v);   // quad_perm [2,3,0,1] : xor lane bit 1
    // xor bit 4: ds_swizzle BitMode xor_mask=0x10, and_mask=0x1F
    v += __int_as_float(__builtin_amdgcn_ds_swizzle(__float_as_int(v), 0x401F));
    // xor bit 5: permlane32_swap exchanges 32-lane halves; old + swapped = step
    auto p = __builtin_amdgcn_permlane32_swap(__float_as_int(v), __float_as_int(v), false, false);
    return __int_as_float(p[0]) + __int_as_float(p[1]);
}

__device__ __forceinline__ float read_lane_f(float v, int l) {
    return __int_as_float(__builtin_amdgcn_readlane(__float_as_int(v), l));
}

// Store one patch's 256-float weight region (broadcast value w), base only
// 4B-aligned because d_out[0] is the loss scalar: 63 aligned float4 + 4 scalars.
// Non-temporal: outputs are never re-read; don't evict inputs from L2/L3.
__device__ __forceinline__ void store_w(float* __restrict__ base, float w, int lane) {
    if (lane < 63) {
        floatx4 v = {w, w, w, w};
        __builtin_nontemporal_store(v, (floatx4*)(base + 3 + (lane << 2)));
    }
    if (lane < 4)
        __builtin_nontemporal_store(w, base + (lane == 3 ? 255 : lane));
}

__global__ __launch_bounds__(256) void patch_main(
    const float* __restrict__ p0, const float* __restrict__ p1, const float* __restrict__ p2,
    float* __restrict__ dout, float* __restrict__ acc, unsigned* __restrict__ cnt)
{
    const int lane  = threadIdx.x & 63;
    const int wv    = threadIdx.x >> 6;
    const int wgid  = blockIdx.x * 4 + wv;      // 0..12287
    const int pbase = wgid * 4;                 // first of 4 adjacent patches
    const int plane = pbase >> 10;
    const int nb    = pbase & 1023;             // multiple of 4, same patch-row
    const int pi    = nb >> 5;
    const int pjb   = nb & 31;

    const int colgrp = lane & 15;               // column group across 4 patches
    const int rowin  = lane >> 4;               // 0..3
    const size_t base = (size_t)plane * PLANE_ELEMS
                      + (size_t)(pi * 16 + rowin) * IMG
                      + (size_t)(pjb * 16 + colgrp * 4);

    // 12 loads up front; each instr = 4 x 256B contiguous segments
    float4 a[4], b[4], c[4];
#pragma unroll
    for (int i = 0; i < 4; ++i) {
        const size_t off = base + (size_t)(4 * i) * IMG;
        a[i] = *(const float4*)(p0 + off);
        b[i] = *(const float4*)(p1 + off);
        c[i] = *(const float4*)(p2 + off);
    }

    // 8 independent raw-moment accumulators over this lane's 16 elements
    float S1 = 0, S2 = 0, Q0 = 0, Q1 = 0, Q2 = 0, P01 = 0, P02 = 0, P12 = 0;
#pragma unroll
    for (int i = 0; i < 4; ++i) {
        const float av[4] = {a[i].x, a[i].y, a[i].z, a[i].w};
        const float bv[4] = {b[i].x, b[i].y, b[i].z, b[i].w};
        const float cv[4] = {c[i].x, c[i].y, c[i].z, c[i].w};
#pragma unroll
        for (int j = 0; j < 4; ++j) {
            S1 += bv[j];               S2 += cv[j];
            Q0  = fmaf(av[j], av[j], Q0);
            Q1  = fmaf(bv[j], bv[j], Q1);
            Q2  = fmaf(cv[j], cv[j], Q2);
            P01 = fmaf(av[j], bv[j], P01);
            P02 = fmaf(av[j], cv[j], P02);
            P12 = fmaf(bv[j], cv[j], P12);
        }
    }

    // One batch of 8 independent segmented butterflies (all 4 patches at once)
    S1 = seg_reduce(S1);  S2 = seg_reduce(S2);
    Q0 = seg_reduce(Q0);  Q1 = seg_reduce(Q1);  Q2 = seg_reduce(Q2);
    P01 = seg_reduce(P01); P02 = seg_reduce(P02); P12 = seg_reduce(P12);

    // Per-lane scalar math for its own patch
    const float mu = S1 * (1.0f / 256.0f);
    const float d1 = fmaxf(Q1 - mu * S1, 0.0f);                       // sum (b-mu)^2
    const float d2 = fmaxf(Q2 - 2.0f * mu * S2 + mu * S1, 0.0f);      // sum (c-mu)^2
    const float sd1 = sqrtf(d1 * (1.0f / 256.0f));
    const float sd2 = sqrtf(d2 * (1.0f / 256.0f));
    const float denom = sd1 + sd2 + EPS;
    const float w1 = sd1 / denom;
    const float w2 = sd2 / denom;
    const float L  = Q0 + w1 * w1 * Q1 + w2 * w2 * Q2
                   - 2.0f * (w1 * P01 + w2 * P02 - w1 * w2 * P12);

    // Broadcast per-patch weights (patch q's rep lane = 4q) + wave loss total
    float w1q[4], w2q[4];
#pragma unroll
    for (int q = 0; q < 4; ++q) {
        w1q[q] = read_lane_f(w1, 4 * q);
        w2q[q] = read_lane_f(w2, 4 * q);
    }
    const float wl = (read_lane_f(L, 0) + read_lane_f(L, 4))
                   + (read_lane_f(L, 8) + read_lane_f(L, 12));

    float* __restrict__ w1o = dout + 1;
    float* __restrict__ w2o = dout + 1 + TOTAL_ELEMS;
    const size_t wb = (size_t)plane * PLANE_ELEMS + (size_t)nb * 256;
#pragma unroll
    for (int q = 0; q < 4; ++q) {
        store_w(w1o + wb + q * 256, w1q[q], lane);
        store_w(w2o + wb + q * 256, w2q[q], lane);
    }

    // Fused loss finalize: native f32 atomic (no CAS loop), counter on its own
    // cache line. Last-arriving block writes dout[0].
    __shared__ float ls[4];
    if (lane == 0) ls[wv] = wl;
    __syncthreads();
    if (threadIdx.x == 0) {
        const float bl = (ls[0] + ls[1]) + (ls[2] + ls[3]);
        atomicAdd(acc, bl);                       // global_atomic_add_f32
        __threadfence();                          // release partial before ticket
        const unsigned old = atomicAdd(cnt, 1u);  // different cache line
        if (old == (unsigned)(NBLOCKS - 1)) {
            __threadfence();                      // acquire all partials
            const float total = atomicAdd(acc, 0.0f);  // coherent read
            dout[0] = total / (float)TOTAL_ELEMS;
        }
    }
}

extern "C" void kernel_launch(void* const* d_in, const int* in_sizes, int n_in,
                              void* d_out, int out_size, void* d_ws, size_t ws_size,
                              hipStream_t stream) {
    const float* p0 = (const float*)d_in[0];   // out (target)
    const float* p1 = (const float*)d_in[1];   // x1
    const float* p2 = (const float*)d_in[2];   // x2
    float* dout   = (float*)d_out;
    float* acc    = (float*)d_ws;                        // line 0
    unsigned* cnt = (unsigned*)((char*)d_ws + 256);      // separate cache line

    (void)hipMemsetAsync(d_ws, 0, 512, stream);          // re-zero each call
    patch_main<<<NBLOCKS, 256, 0, stream>>>(p0, p1, p2, dout, acc, cnt);
}

// Round 9
// 47.507 us; speedup vs baseline: 3.9957x; 3.9957x over previous
//
#include <hip/hip_runtime.h>

// Problem constants (fixed by setup_inputs): (16,3,512,512) f32, PATCH=16
constexpr int IMG         = 512;
constexpr int PLANE_ELEMS = IMG * IMG;          // 262144
constexpr int TOTAL_PATCH = 48 * 1024;          // 49152
constexpr long long TOTAL_ELEMS = 12582912LL;   // 48 * 262144
constexpr float  EPS = 1e-6f;
// 1 wave = 4 horizontally-adjacent patches; 4 waves/block -> 16 patches/block
constexpr int NBLOCKS = TOTAL_PATCH / 16;       // 3072

typedef float floatx4 __attribute__((ext_vector_type(4)));  // native vec for NT store

template <int CTRL>
__device__ __forceinline__ float dpp_add(float v) {
    int x = __builtin_amdgcn_update_dpp(0, __float_as_int(v), CTRL, 0xF, 0xF, false);
    return v + __int_as_float(x);
}

// Segmented butterfly: sums over lane bits {0,1,4,5}; bits {2,3} (= patch id)
// preserved. Every lane ends with its own patch's 16-lane total.
__device__ __forceinline__ float seg_reduce(float v) {
    v = dpp_add<0xB1>(v);   // quad_perm [1,0,3,2] : xor lane bit 0
    v = dpp_add<0x4E>(v);   // quad_perm [2,3,0,1] : xor lane bit 1
    // xor bit 4: ds_swizzle BitMode xor_mask=0x10, and_mask=0x1F
    v += __int_as_float(__builtin_amdgcn_ds_swizzle(__float_as_int(v), 0x401F));
    // xor bit 5: permlane32_swap exchanges 32-lane halves; old + swapped = step
    auto p = __builtin_amdgcn_permlane32_swap(__float_as_int(v), __float_as_int(v), false, false);
    return __int_as_float(p[0]) + __int_as_float(p[1]);
}

__device__ __forceinline__ float read_lane_f(float v, int l) {
    return __int_as_float(__builtin_amdgcn_readlane(__float_as_int(v), l));
}

// Store one patch's 256-float weight region (broadcast value w), base only
// 4B-aligned because d_out[0] is the loss scalar: 63 aligned float4 + 4 scalars.
// Non-temporal: outputs are never re-read; don't evict inputs from L2/L3.
__device__ __forceinline__ void store_w(float* __restrict__ base, float w, int lane) {
    if (lane < 63) {
        floatx4 v = {w, w, w, w};
        __builtin_nontemporal_store(v, (floatx4*)(base + 3 + (lane << 2)));
    }
    if (lane < 4)
        __builtin_nontemporal_store(w, base + (lane == 3 ? 255 : lane));
}

__global__ __launch_bounds__(256) void patch_main(
    const float* __restrict__ p0, const float* __restrict__ p1, const float* __restrict__ p2,
    float* __restrict__ dout, float* __restrict__ partial)
{
    const int lane  = threadIdx.x & 63;
    const int wv    = threadIdx.x >> 6;
    const int wgid  = blockIdx.x * 4 + wv;      // 0..12287
    const int pbase = wgid * 4;                 // first of 4 adjacent patches
    const int plane = pbase >> 10;
    const int nb    = pbase & 1023;             // multiple of 4, same patch-row
    const int pi    = nb >> 5;
    const int pjb   = nb & 31;

    const int colgrp = lane & 15;               // column group across 4 patches
    const int rowin  = lane >> 4;               // 0..3
    const size_t base = (size_t)plane * PLANE_ELEMS
                      + (size_t)(pi * 16 + rowin) * IMG
                      + (size_t)(pjb * 16 + colgrp * 4);

    // 12 loads up front; each instr = 4 x 256B contiguous segments
    float4 a[4], b[4], c[4];
#pragma unroll
    for (int i = 0; i < 4; ++i) {
        const size_t off = base + (size_t)(4 * i) * IMG;
        a[i] = *(const float4*)(p0 + off);
        b[i] = *(const float4*)(p1 + off);
        c[i] = *(const float4*)(p2 + off);
    }

    // 8 independent raw-moment accumulators over this lane's 16 elements
    float S1 = 0, S2 = 0, Q0 = 0, Q1 = 0, Q2 = 0, P01 = 0, P02 = 0, P12 = 0;
#pragma unroll
    for (int i = 0; i < 4; ++i) {
        const float av[4] = {a[i].x, a[i].y, a[i].z, a[i].w};
        const float bv[4] = {b[i].x, b[i].y, b[i].z, b[i].w};
        const float cv[4] = {c[i].x, c[i].y, c[i].z, c[i].w};
#pragma unroll
        for (int j = 0; j < 4; ++j) {
            S1 += bv[j];               S2 += cv[j];
            Q0  = fmaf(av[j], av[j], Q0);
            Q1  = fmaf(bv[j], bv[j], Q1);
            Q2  = fmaf(cv[j], cv[j], Q2);
            P01 = fmaf(av[j], bv[j], P01);
            P02 = fmaf(av[j], cv[j], P02);
            P12 = fmaf(bv[j], cv[j], P12);
        }
    }

    // One batch of 8 independent segmented butterflies (all 4 patches at once)
    S1 = seg_reduce(S1);  S2 = seg_reduce(S2);
    Q0 = seg_reduce(Q0);  Q1 = seg_reduce(Q1);  Q2 = seg_reduce(Q2);
    P01 = seg_reduce(P01); P02 = seg_reduce(P02); P12 = seg_reduce(P12);

    // Per-lane scalar math for its own patch
    const float mu = S1 * (1.0f / 256.0f);
    const float d1 = fmaxf(Q1 - mu * S1, 0.0f);                       // sum (b-mu)^2
    const float d2 = fmaxf(Q2 - 2.0f * mu * S2 + mu * S1, 0.0f);      // sum (c-mu)^2
    const float sd1 = sqrtf(d1 * (1.0f / 256.0f));
    const float sd2 = sqrtf(d2 * (1.0f / 256.0f));
    const float denom = sd1 + sd2 + EPS;
    const float w1 = sd1 / denom;
    const float w2 = sd2 / denom;
    const float L  = Q0 + w1 * w1 * Q1 + w2 * w2 * Q2
                   - 2.0f * (w1 * P01 + w2 * P02 - w1 * w2 * P12);

    // Broadcast per-patch weights (patch q's rep lane = 4q) + wave loss total
    float w1q[4], w2q[4];
#pragma unroll
    for (int q = 0; q < 4; ++q) {
        w1q[q] = read_lane_f(w1, 4 * q);
        w2q[q] = read_lane_f(w2, 4 * q);
    }
    const float wl = (read_lane_f(L, 0) + read_lane_f(L, 4))
                   + (read_lane_f(L, 8) + read_lane_f(L, 12));

    float* __restrict__ w1o = dout + 1;
    float* __restrict__ w2o = dout + 1 + TOTAL_ELEMS;
    const size_t wb = (size_t)plane * PLANE_ELEMS + (size_t)nb * 256;
#pragma unroll
    for (int q = 0; q < 4; ++q) {
        store_w(w1o + wb + q * 256, w1q[q], lane);
        store_w(w2o + wb + q * 256, w2q[q], lane);
    }

    // Per-block loss partial (deterministic, no atomics, no fences)
    __shared__ float ls[4];
    if (lane == 0) ls[wv] = wl;
    __syncthreads();
    if (threadIdx.x == 0)
        partial[blockIdx.x] = (ls[0] + ls[1]) + (ls[2] + ls[3]);
}

__global__ __launch_bounds__(256) void patch_reduce(
    const float* __restrict__ partial, float* __restrict__ dout)
{
    constexpr int NPART = NBLOCKS;  // 3072
    double s = 0.0;
    for (int i = threadIdx.x; i < NPART; i += 256)
        s += (double)partial[i];
#pragma unroll
    for (int m = 1; m < 64; m <<= 1)
        s += __shfl_xor(s, m, 64);
    __shared__ double sm[4];
    if ((threadIdx.x & 63) == 0) sm[threadIdx.x >> 6] = s;
    __syncthreads();
    if (threadIdx.x == 0)
        dout[0] = (float)(((sm[0] + sm[1]) + (sm[2] + sm[3])) / (double)TOTAL_ELEMS);
}

extern "C" void kernel_launch(void* const* d_in, const int* in_sizes, int n_in,
                              void* d_out, int out_size, void* d_ws, size_t ws_size,
                              hipStream_t stream) {
    const float* p0 = (const float*)d_in[0];   // out (target)
    const float* p1 = (const float*)d_in[1];   // x1
    const float* p2 = (const float*)d_in[2];   // x2
    float* dout    = (float*)d_out;
    float* partial = (float*)d_ws;             // 3072 floats

    patch_main<<<NBLOCKS, 256, 0, stream>>>(p0, p1, p2, dout, partial);
    patch_reduce<<<1, 256, 0, stream>>>(partial, dout);
}

// Round 10
// 46.373 us; speedup vs baseline: 4.0934x; 1.0245x over previous
//
#include <hip/hip_runtime.h>

// Problem constants (fixed by setup_inputs): (16,3,512,512) f32, PATCH=16
constexpr int IMG         = 512;
constexpr int PLANE_ELEMS = IMG * IMG;          // 262144
constexpr int TOTAL_PATCH = 48 * 1024;          // 49152
constexpr long long TOTAL_ELEMS = 12582912LL;   // 48 * 262144
constexpr float  EPS = 1e-6f;
// 1 wave = 4 horizontally-adjacent patches; 4 waves/block -> 16 patches/block
constexpr int NBLOCKS = TOTAL_PATCH / 16;       // 3072

template <int CTRL>
__device__ __forceinline__ float dpp_add(float v) {
    int x = __builtin_amdgcn_update_dpp(0, __float_as_int(v), CTRL, 0xF, 0xF, false);
    return v + __int_as_float(x);
}

// Segmented butterfly: sums over lane bits {0,1,4,5}; bits {2,3} (= patch id)
// preserved. Every lane ends with its own patch's 16-lane total.
__device__ __forceinline__ float seg_reduce(float v) {
    v = dpp_add<0xB1>(v);   // quad_perm [1,0,3,2] : xor lane bit 0
    v = dpp_add<0x4E>(v);   // quad_perm [2,3,0,1] : xor lane bit 1
    // xor bit 4: ds_swizzle BitMode xor_mask=0x10, and_mask=0x1F
    v += __int_as_float(__builtin_amdgcn_ds_swizzle(__float_as_int(v), 0x401F));
    // xor bit 5: permlane32_swap exchanges 32-lane halves; old + swapped = step
    auto p = __builtin_amdgcn_permlane32_swap(__float_as_int(v), __float_as_int(v), false, false);
    return __int_as_float(p[0]) + __int_as_float(p[1]);
}

__device__ __forceinline__ float read_lane_f(float v, int l) {
    return __int_as_float(__builtin_amdgcn_readlane(__float_as_int(v), l));
}

// Store one patch's 256-float weight region (broadcast value w), base only
// 4B-aligned because d_out[0] is the loss scalar: 63 aligned float4 + 4 scalars.
// (NT stores tested in R9: +5MB WRITE_SIZE from partial-line scalar NT writes,
// no FETCH gain -> regular stores are better here.)
__device__ __forceinline__ void store_w(float* __restrict__ base, float w, int lane) {
    if (lane < 63) {
        float4 v = make_float4(w, w, w, w);
        *(float4*)(base + 3 + (lane << 2)) = v;      // elements 3..254, 16B-aligned
    }
    if (lane < 4) base[lane == 3 ? 255 : lane] = w;  // head 0,1,2 + tail 255
}

__global__ __launch_bounds__(256) void patch_main(
    const float* __restrict__ p0, const float* __restrict__ p1, const float* __restrict__ p2,
    float* __restrict__ dout, float* __restrict__ partial)
{
    const int lane  = threadIdx.x & 63;
    const int wv    = threadIdx.x >> 6;
    const int wgid  = blockIdx.x * 4 + wv;      // 0..12287
    const int pbase = wgid * 4;                 // first of 4 adjacent patches
    const int plane = pbase >> 10;
    const int nb    = pbase & 1023;             // multiple of 4, same patch-row
    const int pi    = nb >> 5;
    const int pjb   = nb & 31;

    const int colgrp = lane & 15;               // column group across 4 patches
    const int rowin  = lane >> 4;               // 0..3
    const size_t base = (size_t)plane * PLANE_ELEMS
                      + (size_t)(pi * 16 + rowin) * IMG
                      + (size_t)(pjb * 16 + colgrp * 4);

    // 12 loads up front; each instr = 4 x 256B contiguous segments
    float4 a[4], b[4], c[4];
#pragma unroll
    for (int i = 0; i < 4; ++i) {
        const size_t off = base + (size_t)(4 * i) * IMG;
        a[i] = *(const float4*)(p0 + off);
        b[i] = *(const float4*)(p1 + off);
        c[i] = *(const float4*)(p2 + off);
    }

    // 8 independent raw-moment accumulators over this lane's 16 elements
    float S1 = 0, S2 = 0, Q0 = 0, Q1 = 0, Q2 = 0, P01 = 0, P02 = 0, P12 = 0;
#pragma unroll
    for (int i = 0; i < 4; ++i) {
        const float av[4] = {a[i].x, a[i].y, a[i].z, a[i].w};
        const float bv[4] = {b[i].x, b[i].y, b[i].z, b[i].w};
        const float cv[4] = {c[i].x, c[i].y, c[i].z, c[i].w};
#pragma unroll
        for (int j = 0; j < 4; ++j) {
            S1 += bv[j];               S2 += cv[j];
            Q0  = fmaf(av[j], av[j], Q0);
            Q1  = fmaf(bv[j], bv[j], Q1);
            Q2  = fmaf(cv[j], cv[j], Q2);
            P01 = fmaf(av[j], bv[j], P01);
            P02 = fmaf(av[j], cv[j], P02);
            P12 = fmaf(bv[j], cv[j], P12);
        }
    }

    // One batch of 8 independent segmented butterflies (all 4 patches at once)
    S1 = seg_reduce(S1);  S2 = seg_reduce(S2);
    Q0 = seg_reduce(Q0);  Q1 = seg_reduce(Q1);  Q2 = seg_reduce(Q2);
    P01 = seg_reduce(P01); P02 = seg_reduce(P02); P12 = seg_reduce(P12);

    // Per-lane scalar math for its own patch
    const float mu = S1 * (1.0f / 256.0f);
    const float d1 = fmaxf(Q1 - mu * S1, 0.0f);                       // sum (b-mu)^2
    const float d2 = fmaxf(Q2 - 2.0f * mu * S2 + mu * S1, 0.0f);      // sum (c-mu)^2
    const float sd1 = sqrtf(d1 * (1.0f / 256.0f));
    const float sd2 = sqrtf(d2 * (1.0f / 256.0f));
    const float denom = sd1 + sd2 + EPS;
    const float w1 = sd1 / denom;
    const float w2 = sd2 / denom;
    const float L  = Q0 + w1 * w1 * Q1 + w2 * w2 * Q2
                   - 2.0f * (w1 * P01 + w2 * P02 - w1 * w2 * P12);

    // Broadcast per-patch weights (patch q's rep lane = 4q) + wave loss total
    float w1q[4], w2q[4];
#pragma unroll
    for (int q = 0; q < 4; ++q) {
        w1q[q] = read_lane_f(w1, 4 * q);
        w2q[q] = read_lane_f(w2, 4 * q);
    }
    const float wl = (read_lane_f(L, 0) + read_lane_f(L, 4))
                   + (read_lane_f(L, 8) + read_lane_f(L, 12));

    float* __restrict__ w1o = dout + 1;
    float* __restrict__ w2o = dout + 1 + TOTAL_ELEMS;
    const size_t wb = (size_t)plane * PLANE_ELEMS + (size_t)nb * 256;
#pragma unroll
    for (int q = 0; q < 4; ++q) {
        store_w(w1o + wb + q * 256, w1q[q], lane);
        store_w(w2o + wb + q * 256, w2q[q], lane);
    }

    // Per-block loss partial (deterministic, no atomics, no fences)
    __shared__ float ls[4];
    if (lane == 0) ls[wv] = wl;
    __syncthreads();
    if (threadIdx.x == 0)
        partial[blockIdx.x] = (ls[0] + ls[1]) + (ls[2] + ls[3]);
}

__global__ __launch_bounds__(256) void patch_reduce(
    const float* __restrict__ partial, float* __restrict__ dout)
{
    constexpr int NPART = NBLOCKS;  // 3072
    double s = 0.0;
    for (int i = threadIdx.x; i < NPART; i += 256)
        s += (double)partial[i];
#pragma unroll
    for (int m = 1; m < 64; m <<= 1)
        s += __shfl_xor(s, m, 64);
    __shared__ double sm[4];
    if ((threadIdx.x & 63) == 0) sm[threadIdx.x >> 6] = s;
    __syncthreads();
    if (threadIdx.x == 0)
        dout[0] = (float)(((sm[0] + sm[1]) + (sm[2] + sm[3])) / (double)TOTAL_ELEMS);
}

extern "C" void kernel_launch(void* const* d_in, const int* in_sizes, int n_in,
                              void* d_out, int out_size, void* d_ws, size_t ws_size,
                              hipStream_t stream) {
    const float* p0 = (const float*)d_in[0];   // out (target)
    const float* p1 = (const float*)d_in[1];   // x1
    const float* p2 = (const float*)d_in[2];   // x2
    float* dout    = (float*)d_out;
    float* partial = (float*)d_ws;             // 3072 floats

    patch_main<<<NBLOCKS, 256, 0, stream>>>(p0, p1, p2, dout, partial);
    patch_reduce<<<1, 256, 0, stream>>>(partial, dout);
}